// Round 4
// baseline (518.278 us; speedup 1.0000x reference)
//
#include <hip/hip_runtime.h>
#include <hip/hip_bf16.h>

typedef __attribute__((ext_vector_type(8))) short bf16x8;
typedef __attribute__((ext_vector_type(4))) float f32x4;

#define ELL_W 64   // Poisson(16) in-degree: P(deg>64) ~ 1e-20, safe

// ---------------- helpers ----------------

__device__ __forceinline__ float bf2f(unsigned short u) {
    return __uint_as_float(((unsigned int)u) << 16);
}
__device__ __forceinline__ unsigned short f2bf(float f) {
    unsigned int u = __float_as_uint(f);
    unsigned int r = (u + 0x7fffu + ((u >> 16) & 1u)) >> 16;  // RNE
    return (unsigned short)r;
}

__global__ void zero_kernel(int* __restrict__ a, int n) {
    int i = blockIdx.x * blockDim.x + threadIdx.x;
    if (i < n) a[i] = 0;
}

// ---------------- ELL build (single pass, atomics) ----------------
// edge_index int32, flat [2,E]: src = ei[e], dst = ei[E+e].

__global__ void fill_ell_kernel(const int* __restrict__ ei, int E, int N,
                                int* __restrict__ cursor, int* __restrict__ ell) {
    int e = blockIdx.x * blockDim.x + threadIdx.x;
    int stride = gridDim.x * blockDim.x;
    for (; e < E; e += stride) {
        int s = ei[e];
        int d = ei[E + e];
        if ((unsigned)s >= (unsigned)N || (unsigned)d >= (unsigned)N) continue;
        int pos = atomicAdd(&cursor[d], 1);
        if (pos < ELL_W) ell[(size_t)d * ELL_W + pos] = s;
    }
}

__global__ void compute_dinv_kernel(const int* __restrict__ deg, float* __restrict__ dinv, int N) {
    int i = blockIdx.x * blockDim.x + threadIdx.x;
    if (i < N) dinv[i] = rsqrtf((float)(deg[i] + 1));   // +1 self-loop
}

// ---------------- W1 -> bf16 fragment-ordered pack ----------------
// Fragment layout for mfma_f32_16x16x32_bf16 B-operand:
// b-frag elem: B[k][n], lane (nn = lane&15 -> n within 16-tile, cc = lane>>4),
//              k = k0*32 + cc*8 + i (i=0..7 consecutive bf16 in the lane's 16B).
// flat[( (j*4 + k0)*64 + lane )*8 + i],  j = n-tile (0..7), k0 = k-step (0..3).

__global__ void build_wfrag_kernel(const float* __restrict__ W1, unsigned short* __restrict__ wfrag) {
    int t = blockIdx.x * blockDim.x + threadIdx.x;   // 0..2047, 8 elems each
    if (t >= 2048) return;
    int ln = t & 63;
    int blk = t >> 6;          // j*4 + k0
    int j = blk >> 2, k0 = blk & 3;
    int nn = ln & 15, cc = ln >> 4;
    int n = j * 16 + nn;
    unsigned short tmp[8];
#pragma unroll
    for (int i = 0; i < 8; ++i) {
        int k = k0 * 32 + cc * 8 + i;
        tmp[i] = f2bf(W1[(size_t)k * 128 + n]);
    }
    *(uint4*)&wfrag[(size_t)t * 8] = *(const uint4*)tmp;
}

// ---------------- GEMM1 (MFMA): h1[N,128](bf16) = bf16(X) @ bf16(W1) ------
// Block 256 = 4 waves; wave owns 32 rows (2 row-tiles of 16) x 128 cols.
// A-frag loaded from global fp32 (coalesced 128B/row per k-step), cast inline.
// B staged in LDS in fragment order -> ds_read_b128 at lane*16: conflict-free.

__global__ __launch_bounds__(256) void gemm1_mfma_kernel(const float* __restrict__ X,
                                                         const unsigned short* __restrict__ wfrag,
                                                         unsigned short* __restrict__ H, int N) {
    __shared__ __align__(16) unsigned short wl[16384];   // 32 KB
    int tid = threadIdx.x;
    {
        uint4* dst = (uint4*)wl;
        const uint4* src = (const uint4*)wfrag;
        for (int idx = tid; idx < 2048; idx += 256) dst[idx] = src[idx];
    }
    __syncthreads();

    int lane = tid & 63;
    int wave = tid >> 6;
    int m0 = blockIdx.x * 128 + wave * 32;
    int mrow = lane & 15;
    int kc = lane >> 4;

    f32x4 acc[2][8];
#pragma unroll
    for (int rt = 0; rt < 2; ++rt)
#pragma unroll
        for (int j = 0; j < 8; ++j) acc[rt][j] = (f32x4)(0.f);

#pragma unroll
    for (int k0 = 0; k0 < 4; ++k0) {
        bf16x8 a[2];
#pragma unroll
        for (int rt = 0; rt < 2; ++rt) {
            int row = m0 + rt * 16 + mrow;
            bf16x8 av = (bf16x8)(short)0;
            if (row < N) {
                const float4* p = (const float4*)&X[(size_t)row * 128 + k0 * 32 + kc * 8];
                float4 v0 = p[0], v1 = p[1];
                av[0] = (short)f2bf(v0.x); av[1] = (short)f2bf(v0.y);
                av[2] = (short)f2bf(v0.z); av[3] = (short)f2bf(v0.w);
                av[4] = (short)f2bf(v1.x); av[5] = (short)f2bf(v1.y);
                av[6] = (short)f2bf(v1.z); av[7] = (short)f2bf(v1.w);
            }
            a[rt] = av;
        }
#pragma unroll
        for (int j = 0; j < 8; ++j) {
            bf16x8 b = *(const bf16x8*)&wl[((size_t)(j * 4 + k0) * 64 + lane) * 8];
            acc[0][j] = __builtin_amdgcn_mfma_f32_16x16x32_bf16(a[0], b, acc[0][j], 0, 0, 0);
            acc[1][j] = __builtin_amdgcn_mfma_f32_16x16x32_bf16(a[1], b, acc[1][j], 0, 0, 0);
        }
    }

    // C/D layout: col = lane&15, row = 4*(lane>>4) + r
#pragma unroll
    for (int rt = 0; rt < 2; ++rt) {
#pragma unroll
        for (int r = 0; r < 4; ++r) {
            int row = m0 + rt * 16 + 4 * kc + r;
            if (row < N) {
#pragma unroll
                for (int j = 0; j < 8; ++j) {
                    H[(size_t)row * 128 + j * 16 + mrow] = f2bf(acc[rt][j][r]);
                }
            }
        }
    }
}

// ---------------- Fused: g1 = relu(Ahat*h1 + b1); h2 = g1 @ W2 (bf16 out) ---
// One wave per node (lane owns feats 2l,2l+1). g1 stays fp32 in registers.
// GEMM2 via 512B LDS redistribution: lane (n=lane&15, q=lane>>4) dots
// g[q*32..q*32+31] with its preloaded W2 column slice; 2 shuffles to reduce.

__global__ __launch_bounds__(256) void agg128_fused_kernel(const unsigned short* __restrict__ H,
                                                           const int* __restrict__ ell,
                                                           const int* __restrict__ deg,
                                                           const float* __restrict__ dinv,
                                                           const float* __restrict__ b1,
                                                           const float* __restrict__ W2,
                                                           unsigned short* __restrict__ h2out, int N) {
    __shared__ float gbuf[4][128];
    int lane = threadIdx.x & 63;
    int w = threadIdx.x >> 6;
    int i = blockIdx.x * 4 + w;
    if (i >= N) return;

    int n = lane & 15;
    int q = lane >> 4;

    // preload W2 slice: w2r[m] = W2[q*32+m][n]
    float w2r[32];
#pragma unroll
    for (int m = 0; m < 32; ++m) w2r[m] = W2[(size_t)(q * 32 + m) * 16 + n];

    int d = deg[i]; if (d > ELL_W) d = ELL_W;
    float di = dinv[i];

    ushort2 hv = *(const ushort2*)&H[(size_t)i * 128 + 2 * lane];
    float ax = di * bf2f(hv.x);
    float ay = di * bf2f(hv.y);

    const int* row = &ell[(size_t)i * ELL_W];
#pragma unroll 4
    for (int e = 0; e < d; ++e) {
        int s = row[e];
        float wt = dinv[s];
        ushort2 h2 = *(const ushort2*)&H[(size_t)s * 128 + 2 * lane];
        ax += wt * bf2f(h2.x);
        ay += wt * bf2f(h2.y);
    }
    float2 bb = *(const float2*)&b1[2 * lane];
    float gx = fmaxf(di * ax + bb.x, 0.f);
    float gy = fmaxf(di * ay + bb.y, 0.f);

    *(float2*)&gbuf[w][2 * lane] = make_float2(gx, gy);
    asm volatile("s_waitcnt lgkmcnt(0)" ::: "memory");   // wave-internal LDS RAW

    // dot: bank-staggered reads (rotate by 2 float4 per q -> conflict-free)
    float partial = 0.f;
#pragma unroll
    for (int tt = 0; tt < 8; ++tt) {
        int t = (tt + 2 * q) & 7;
        float4 gv = *(const float4*)&gbuf[w][q * 32 + t * 4];
        partial += gv.x * w2r[t * 4 + 0] + gv.y * w2r[t * 4 + 1] +
                   gv.z * w2r[t * 4 + 2] + gv.w * w2r[t * 4 + 3];
    }
    partial += __shfl_xor(partial, 16, 64);
    partial += __shfl_xor(partial, 32, 64);
    if (lane < 16) h2out[(size_t)i * 16 + lane] = f2bf(partial);
}

// ---------------- agg16: out = Ahat*h2 + b2 (fp32 out) ----------------
// One wave per node; group q handles edges e = q, q+4, ...

__global__ __launch_bounds__(256) void agg16_kernel(const unsigned short* __restrict__ H,
                                                    const int* __restrict__ ell,
                                                    const int* __restrict__ deg,
                                                    const float* __restrict__ dinv,
                                                    const float* __restrict__ b2,
                                                    float* __restrict__ out, int N) {
    int lane = threadIdx.x & 63;
    int i = blockIdx.x * 4 + (threadIdx.x >> 6);
    if (i >= N) return;
    int t = lane & 15;
    int q = lane >> 4;

    int d = deg[i]; if (d > ELL_W) d = ELL_W;
    float di = dinv[i];
    const int* row = &ell[(size_t)i * ELL_W];

    float partial = (q == 0) ? di * bf2f(H[(size_t)i * 16 + t]) : 0.f;
#pragma unroll 2
    for (int e = q; e < d; e += 4) {
        int s = row[e];
        float wt = dinv[s];
        partial += wt * bf2f(H[(size_t)s * 16 + t]);
    }
    partial += __shfl_xor(partial, 16, 64);
    partial += __shfl_xor(partial, 32, 64);
    if (lane < 16) out[(size_t)i * 16 + t] = di * partial + b2[t];
}

// ---------------- Launch ----------------

extern "C" void kernel_launch(void* const* d_in, const int* in_sizes, int n_in,
                              void* d_out, int out_size, void* d_ws, size_t ws_size,
                              hipStream_t stream) {
    const float* x = (const float*)d_in[0];
    const int* ei = (const int*)d_in[1];
    const float* W1 = (const float*)d_in[2];
    const float* b1 = (const float*)d_in[3];
    const float* W2 = (const float*)d_in[4];
    const float* b2 = (const float*)d_in[5];
    float* out = (float*)d_out;

    const int N = in_sizes[0] / 128;   // 100000
    const int E = in_sizes[1] / 2;     // 1600000

    char* base = (char*)d_ws;
    size_t off = 0;
    auto align_up = [](size_t v) { return (v + 255) & ~(size_t)255; };

    int* cursor = (int*)(base + off);                     off = align_up(off + (size_t)N * 4);
    float* dinv = (float*)(base + off);                   off = align_up(off + (size_t)N * 4);
    int* ell = (int*)(base + off);                        off = align_up(off + (size_t)N * ELL_W * 4);
    unsigned short* wfrag = (unsigned short*)(base + off); off = align_up(off + (size_t)16384 * 2);
    unsigned short* h1 = (unsigned short*)(base + off);   off = align_up(off + (size_t)N * 128 * 2);
    unsigned short* h2 = (unsigned short*)(base + off);   off = align_up(off + (size_t)N * 16 * 2);

    zero_kernel<<<(N + 255) / 256, 256, 0, stream>>>(cursor, N);
    build_wfrag_kernel<<<8, 256, 0, stream>>>(W1, wfrag);
    fill_ell_kernel<<<2048, 256, 0, stream>>>(ei, E, N, cursor, ell);
    compute_dinv_kernel<<<(N + 255) / 256, 256, 0, stream>>>(cursor, dinv, N);

    gemm1_mfma_kernel<<<(N + 127) / 128, 256, 0, stream>>>(x, wfrag, h1, N);
    agg128_fused_kernel<<<(N + 3) / 4, 256, 0, stream>>>(h1, ell, cursor, dinv, b1, W2, h2, N);
    agg16_kernel<<<(N + 3) / 4, 256, 0, stream>>>(h2, ell, cursor, dinv, b2, out, N);
}

// Round 5
// 316.345 us; speedup vs baseline: 1.6383x; 1.6383x over previous
//
#include <hip/hip_runtime.h>
#include <hip/hip_bf16.h>

typedef __attribute__((ext_vector_type(8))) short bf16x8;
typedef __attribute__((ext_vector_type(4))) float f32x4;

#define ELL_W 64   // Poisson(16) in-degree: P(deg>64) ~ 1e-20, safe

// ---------------- helpers ----------------

__device__ __forceinline__ float bf2f(unsigned short u) {
    return __uint_as_float(((unsigned int)u) << 16);
}
__device__ __forceinline__ unsigned short f2bf(float f) {
    unsigned int u = __float_as_uint(f);
    unsigned int r = (u + 0x7fffu + ((u >> 16) & 1u)) >> 16;  // RNE
    return (unsigned short)r;
}

__global__ void zero_kernel(int* __restrict__ a, int n) {
    int i = blockIdx.x * blockDim.x + threadIdx.x;
    if (i < n) a[i] = 0;
}

// ---------------- ELL build (single pass, atomics) ----------------
// edge_index int32, flat [2,E]: src = ei[e], dst = ei[E+e].

__global__ void fill_ell_kernel(const int* __restrict__ ei, int E, int N,
                                int* __restrict__ cursor, int* __restrict__ ell) {
    int e = blockIdx.x * blockDim.x + threadIdx.x;
    int stride = gridDim.x * blockDim.x;
    for (; e < E; e += stride) {
        int s = ei[e];
        int d = ei[E + e];
        if ((unsigned)s >= (unsigned)N || (unsigned)d >= (unsigned)N) continue;
        int pos = atomicAdd(&cursor[d], 1);
        if (pos < ELL_W) ell[(size_t)d * ELL_W + pos] = s;
    }
}

__global__ void compute_dinv_kernel(const int* __restrict__ deg, float* __restrict__ dinv, int N) {
    int i = blockIdx.x * blockDim.x + threadIdx.x;
    if (i < N) dinv[i] = rsqrtf((float)(deg[i] + 1));   // +1 self-loop
}

// ---------------- W1 -> bf16 fragment-ordered pack ----------------
// B-frag for mfma_f32_16x16x32_bf16: lane (nn=lane&15 -> n, cc=lane>>4),
// k = k0*32 + cc*8 + i. flat[((j*4+k0)*64 + lane)*8 + i], j = n-tile.

__global__ void build_wfrag_kernel(const float* __restrict__ W1, unsigned short* __restrict__ wfrag) {
    int t = blockIdx.x * blockDim.x + threadIdx.x;   // 0..2047, 8 elems each
    if (t >= 2048) return;
    int ln = t & 63;
    int blk = t >> 6;          // j*4 + k0
    int j = blk >> 2, k0 = blk & 3;
    int nn = ln & 15, cc = ln >> 4;
    int n = j * 16 + nn;
    unsigned short tmp[8];
#pragma unroll
    for (int i = 0; i < 8; ++i) {
        int k = k0 * 32 + cc * 8 + i;
        tmp[i] = f2bf(W1[(size_t)k * 128 + n]);
    }
    *(uint4*)&wfrag[(size_t)t * 8] = *(const uint4*)tmp;
}

// ---------------- GEMM1 (MFMA): h1[N,128](bf16) = bf16(X) @ bf16(W1) ------

__global__ __launch_bounds__(256) void gemm1_mfma_kernel(const float* __restrict__ X,
                                                         const unsigned short* __restrict__ wfrag,
                                                         unsigned short* __restrict__ H, int N) {
    __shared__ __align__(16) unsigned short wl[16384];   // 32 KB
    int tid = threadIdx.x;
    {
        uint4* dst = (uint4*)wl;
        const uint4* src = (const uint4*)wfrag;
        for (int idx = tid; idx < 2048; idx += 256) dst[idx] = src[idx];
    }
    __syncthreads();

    int lane = tid & 63;
    int wave = tid >> 6;
    int m0 = blockIdx.x * 128 + wave * 32;
    int mrow = lane & 15;
    int kc = lane >> 4;

    f32x4 acc[2][8];
#pragma unroll
    for (int rt = 0; rt < 2; ++rt)
#pragma unroll
        for (int j = 0; j < 8; ++j) acc[rt][j] = (f32x4)(0.f);

#pragma unroll
    for (int k0 = 0; k0 < 4; ++k0) {
        bf16x8 a[2];
#pragma unroll
        for (int rt = 0; rt < 2; ++rt) {
            int row = m0 + rt * 16 + mrow;
            bf16x8 av = (bf16x8)(short)0;
            if (row < N) {
                const float4* p = (const float4*)&X[(size_t)row * 128 + k0 * 32 + kc * 8];
                float4 v0 = p[0], v1 = p[1];
                av[0] = (short)f2bf(v0.x); av[1] = (short)f2bf(v0.y);
                av[2] = (short)f2bf(v0.z); av[3] = (short)f2bf(v0.w);
                av[4] = (short)f2bf(v1.x); av[5] = (short)f2bf(v1.y);
                av[6] = (short)f2bf(v1.z); av[7] = (short)f2bf(v1.w);
            }
            a[rt] = av;
        }
#pragma unroll
        for (int j = 0; j < 8; ++j) {
            bf16x8 b = *(const bf16x8*)&wl[((size_t)(j * 4 + k0) * 64 + lane) * 8];
            acc[0][j] = __builtin_amdgcn_mfma_f32_16x16x32_bf16(a[0], b, acc[0][j], 0, 0, 0);
            acc[1][j] = __builtin_amdgcn_mfma_f32_16x16x32_bf16(a[1], b, acc[1][j], 0, 0, 0);
        }
    }

    // C/D layout: col = lane&15, row = 4*(lane>>4) + r
#pragma unroll
    for (int rt = 0; rt < 2; ++rt) {
#pragma unroll
        for (int r = 0; r < 4; ++r) {
            int row = m0 + rt * 16 + 4 * kc + r;
            if (row < N) {
#pragma unroll
                for (int j = 0; j < 8; ++j) {
                    H[(size_t)row * 128 + j * 16 + mrow] = f2bf(acc[rt][j][r]);
                }
            }
        }
    }
}

// ---------------- Fused: g1 = relu(Ahat*h1 + b1); h2 = g1 @ W2 (bf16 out) ---
// One wave per node (lane owns feats 2l,2l+1). g1 stays fp32 in registers.
// GEMM2 via 512B LDS redistribution. ALL w2r indices are compile-time
// constants (rule #20: runtime-indexed arrays go to scratch). Bank stagger
// is folded into the PRELOAD ADDRESS (runtime addr ok, reg index constant):
//   w2r[m] = W2[(q*32 + ((m + 8q) & 31)) * 16 + n]
//   dot:  gbuf[q*32 + ((t*4 + 8q) & 31)] . w2r[t*4 .. t*4+3]

__global__ __launch_bounds__(256) void agg128_fused_kernel(const unsigned short* __restrict__ H,
                                                           const int* __restrict__ ell,
                                                           const int* __restrict__ deg,
                                                           const float* __restrict__ dinv,
                                                           const float* __restrict__ b1,
                                                           const float* __restrict__ W2,
                                                           unsigned short* __restrict__ h2out, int N) {
    __shared__ float gbuf[4][128];
    int lane = threadIdx.x & 63;
    int w = threadIdx.x >> 6;
    int i = blockIdx.x * 4 + w;
    if (i >= N) return;

    int n = lane & 15;
    int q = lane >> 4;

    // preload W2 slice, rotated by 8q within the q-group's 32 rows
    float w2r[32];
#pragma unroll
    for (int m = 0; m < 32; ++m) {
        int mm = (m + 8 * q) & 31;                 // runtime address, constant index
        w2r[m] = W2[(size_t)(q * 32 + mm) * 16 + n];
    }

    int d = deg[i]; if (d > ELL_W) d = ELL_W;
    float di = dinv[i];

    ushort2 hv = *(const ushort2*)&H[(size_t)i * 128 + 2 * lane];
    float ax = di * bf2f(hv.x);
    float ay = di * bf2f(hv.y);

    const int* row = &ell[(size_t)i * ELL_W];
#pragma unroll 4
    for (int e = 0; e < d; ++e) {
        int s = row[e];
        float wt = dinv[s];
        ushort2 h2 = *(const ushort2*)&H[(size_t)s * 128 + 2 * lane];
        ax += wt * bf2f(h2.x);
        ay += wt * bf2f(h2.y);
    }
    float2 bb = *(const float2*)&b1[2 * lane];
    float gx = fmaxf(di * ax + bb.x, 0.f);
    float gy = fmaxf(di * ay + bb.y, 0.f);

    *(float2*)&gbuf[w][2 * lane] = make_float2(gx, gy);
    asm volatile("s_waitcnt lgkmcnt(0)" ::: "memory");   // wave-internal LDS RAW

    float partial = 0.f;
#pragma unroll
    for (int t = 0; t < 8; ++t) {
        int off = (t * 4 + 8 * q) & 31;                  // staggered: conflict-free
        float4 gv = *(const float4*)&gbuf[w][q * 32 + off];
        partial += gv.x * w2r[t * 4 + 0] + gv.y * w2r[t * 4 + 1] +
                   gv.z * w2r[t * 4 + 2] + gv.w * w2r[t * 4 + 3];
    }
    partial += __shfl_xor(partial, 16, 64);
    partial += __shfl_xor(partial, 32, 64);
    if (lane < 16) h2out[(size_t)i * 16 + lane] = f2bf(partial);
}

// ---------------- agg16: out = Ahat*h2 + b2 (fp32 out) ----------------

__global__ __launch_bounds__(256) void agg16_kernel(const unsigned short* __restrict__ H,
                                                    const int* __restrict__ ell,
                                                    const int* __restrict__ deg,
                                                    const float* __restrict__ dinv,
                                                    const float* __restrict__ b2,
                                                    float* __restrict__ out, int N) {
    int lane = threadIdx.x & 63;
    int i = blockIdx.x * 4 + (threadIdx.x >> 6);
    if (i >= N) return;
    int t = lane & 15;
    int q = lane >> 4;

    int d = deg[i]; if (d > ELL_W) d = ELL_W;
    float di = dinv[i];
    const int* row = &ell[(size_t)i * ELL_W];

    float partial = (q == 0) ? di * bf2f(H[(size_t)i * 16 + t]) : 0.f;
#pragma unroll 2
    for (int e = q; e < d; e += 4) {
        int s = row[e];
        float wt = dinv[s];
        partial += wt * bf2f(H[(size_t)s * 16 + t]);
    }
    partial += __shfl_xor(partial, 16, 64);
    partial += __shfl_xor(partial, 32, 64);
    if (lane < 16) out[(size_t)i * 16 + t] = di * partial + b2[t];
}

// ---------------- Launch ----------------

extern "C" void kernel_launch(void* const* d_in, const int* in_sizes, int n_in,
                              void* d_out, int out_size, void* d_ws, size_t ws_size,
                              hipStream_t stream) {
    const float* x = (const float*)d_in[0];
    const int* ei = (const int*)d_in[1];
    const float* W1 = (const float*)d_in[2];
    const float* b1 = (const float*)d_in[3];
    const float* W2 = (const float*)d_in[4];
    const float* b2 = (const float*)d_in[5];
    float* out = (float*)d_out;

    const int N = in_sizes[0] / 128;   // 100000
    const int E = in_sizes[1] / 2;     // 1600000

    char* base = (char*)d_ws;
    size_t off = 0;
    auto align_up = [](size_t v) { return (v + 255) & ~(size_t)255; };

    int* cursor = (int*)(base + off);                     off = align_up(off + (size_t)N * 4);
    float* dinv = (float*)(base + off);                   off = align_up(off + (size_t)N * 4);
    int* ell = (int*)(base + off);                        off = align_up(off + (size_t)N * ELL_W * 4);
    unsigned short* wfrag = (unsigned short*)(base + off); off = align_up(off + (size_t)16384 * 2);
    unsigned short* h1 = (unsigned short*)(base + off);   off = align_up(off + (size_t)N * 128 * 2);
    unsigned short* h2 = (unsigned short*)(base + off);   off = align_up(off + (size_t)N * 16 * 2);

    zero_kernel<<<(N + 255) / 256, 256, 0, stream>>>(cursor, N);
    build_wfrag_kernel<<<8, 256, 0, stream>>>(W1, wfrag);
    fill_ell_kernel<<<2048, 256, 0, stream>>>(ei, E, N, cursor, ell);
    compute_dinv_kernel<<<(N + 255) / 256, 256, 0, stream>>>(cursor, dinv, N);

    gemm1_mfma_kernel<<<(N + 127) / 128, 256, 0, stream>>>(x, wfrag, h1, N);
    agg128_fused_kernel<<<(N + 3) / 4, 256, 0, stream>>>(h1, ell, cursor, dinv, b1, W2, h2, N);
    agg16_kernel<<<(N + 3) / 4, 256, 0, stream>>>(h2, ell, cursor, dinv, b2, out, N);
}

// Round 6
// 231.405 us; speedup vs baseline: 2.2397x; 1.3671x over previous
//
#include <hip/hip_runtime.h>
#include <hip/hip_bf16.h>

typedef __attribute__((ext_vector_type(8))) short bf16x8;
typedef __attribute__((ext_vector_type(4))) float f32x4;

#define ELL_W 64        // Poisson(16) in-degree: P(deg>64) ~ 1e-20
#define BSH   8         // 256 dst-nodes per bucket
#define BCAP  4608      // bucket capacity: mean 4096 + 8 sigma
#define CHUNK 4096      // edges per block in p1

// ---------------- helpers ----------------

__device__ __forceinline__ float bf2f(unsigned short u) {
    return __uint_as_float(((unsigned int)u) << 16);
}
__device__ __forceinline__ unsigned short f2bf(float f) {
    unsigned int u = __float_as_uint(f);
    unsigned int r = (u + 0x7fffu + ((u >> 16) & 1u)) >> 16;  // RNE
    return (unsigned short)r;
}

__global__ void zero_kernel(int* __restrict__ a, int n) {
    int i = blockIdx.x * blockDim.x + threadIdx.x;
    if (i < n) a[i] = 0;
}

// ---------------- P1: partition edges into dst-buckets ----------------
// record = (src << 8) | (dst & 255); bucket = dst >> 8.
// Per-block LDS histogram -> one global atomic per touched bucket -> dense writes.

__global__ __launch_bounds__(256) void p1_partition_kernel(const int* __restrict__ ei, int E, int N, int NB,
                                                           int* __restrict__ gcur, int* __restrict__ bucket) {
    __shared__ int hist[512];
    __shared__ int gbase[512];
    __shared__ int cur2[512];
    int tid = threadIdx.x;
    int c0 = blockIdx.x * CHUNK;

    for (int i = tid; i < NB; i += 256) { hist[i] = 0; cur2[i] = 0; }
    __syncthreads();

    int rec[16], bkt[16];
#pragma unroll
    for (int k = 0; k < 16; ++k) {
        int e = c0 + k * 256 + tid;
        int b = -1, r = 0;
        if (e < E) {
            int s = ei[e], d = ei[E + e];
            if ((unsigned)s < (unsigned)N && (unsigned)d < (unsigned)N) {
                b = d >> BSH;
                r = (s << BSH) | (d & ((1 << BSH) - 1));
            }
        }
        bkt[k] = b; rec[k] = r;
        if (b >= 0) atomicAdd(&hist[b], 1);
    }
    __syncthreads();

    // reserve dense global ranges, one padded atomic per touched bucket
    for (int i = tid; i < NB; i += 256) {
        int c = hist[i];
        gbase[i] = (c > 0) ? atomicAdd(&gcur[i * 16], c) : 0;
    }
    __syncthreads();

#pragma unroll
    for (int k = 0; k < 16; ++k) {
        int b = bkt[k];
        if (b >= 0) {
            int r = atomicAdd(&cur2[b], 1);
            int pos = gbase[b] + r;
            if (pos < BCAP) bucket[(size_t)b * BCAP + pos] = rec[k];
        }
    }
}

// ---------------- P2: bucket -> ELL (one block per bucket) ----------------
// The 64KB ELL region of one bucket is written by ONE block/XCD -> L2-resident.

__global__ __launch_bounds__(256) void p2_ell_kernel(const int* __restrict__ bucket,
                                                     const int* __restrict__ gcur, int N,
                                                     int* __restrict__ cursor, int* __restrict__ ell) {
    int b = blockIdx.x;
    int cnt = gcur[b * 16]; if (cnt > BCAP) cnt = BCAP;
    const int* reg = &bucket[(size_t)b * BCAP];
    for (int k = threadIdx.x; k < cnt; k += 256) {
        int rec = reg[k];
        int s = (int)(((unsigned)rec) >> BSH);
        int dst = (b << BSH) | (rec & ((1 << BSH) - 1));
        if (dst < N) {
            int pos = atomicAdd(&cursor[dst], 1);
            if (pos < ELL_W) ell[(size_t)dst * ELL_W + pos] = s;
        }
    }
}

__global__ void compute_dinv_kernel(const int* __restrict__ deg, float* __restrict__ dinv, int N) {
    int i = blockIdx.x * blockDim.x + threadIdx.x;
    if (i < N) dinv[i] = rsqrtf((float)(deg[i] + 1));   // +1 self-loop
}

// ---------------- W1 -> bf16 fragment-ordered pack ----------------

__global__ void build_wfrag_kernel(const float* __restrict__ W1, unsigned short* __restrict__ wfrag) {
    int t = blockIdx.x * blockDim.x + threadIdx.x;   // 0..2047, 8 elems each
    if (t >= 2048) return;
    int ln = t & 63;
    int blk = t >> 6;          // j*4 + k0
    int j = blk >> 2, k0 = blk & 3;
    int nn = ln & 15, cc = ln >> 4;
    int n = j * 16 + nn;
    unsigned short tmp[8];
#pragma unroll
    for (int i = 0; i < 8; ++i) {
        int k = k0 * 32 + cc * 8 + i;
        tmp[i] = f2bf(W1[(size_t)k * 128 + n]);
    }
    *(uint4*)&wfrag[(size_t)t * 8] = *(const uint4*)tmp;
}

// ---------------- GEMM1 (MFMA): h1[N,128](bf16) = bf16(X) @ bf16(W1) ------

__global__ __launch_bounds__(256) void gemm1_mfma_kernel(const float* __restrict__ X,
                                                         const unsigned short* __restrict__ wfrag,
                                                         unsigned short* __restrict__ H, int N) {
    __shared__ __align__(16) unsigned short wl[16384];   // 32 KB
    int tid = threadIdx.x;
    {
        uint4* dst = (uint4*)wl;
        const uint4* src = (const uint4*)wfrag;
        for (int idx = tid; idx < 2048; idx += 256) dst[idx] = src[idx];
    }
    __syncthreads();

    int lane = tid & 63;
    int wave = tid >> 6;
    int m0 = blockIdx.x * 128 + wave * 32;
    int mrow = lane & 15;
    int kc = lane >> 4;

    f32x4 acc[2][8];
#pragma unroll
    for (int rt = 0; rt < 2; ++rt)
#pragma unroll
        for (int j = 0; j < 8; ++j) acc[rt][j] = (f32x4)(0.f);

#pragma unroll
    for (int k0 = 0; k0 < 4; ++k0) {
        bf16x8 a[2];
#pragma unroll
        for (int rt = 0; rt < 2; ++rt) {
            int row = m0 + rt * 16 + mrow;
            bf16x8 av = (bf16x8)(short)0;
            if (row < N) {
                const float4* p = (const float4*)&X[(size_t)row * 128 + k0 * 32 + kc * 8];
                float4 v0 = p[0], v1 = p[1];
                av[0] = (short)f2bf(v0.x); av[1] = (short)f2bf(v0.y);
                av[2] = (short)f2bf(v0.z); av[3] = (short)f2bf(v0.w);
                av[4] = (short)f2bf(v1.x); av[5] = (short)f2bf(v1.y);
                av[6] = (short)f2bf(v1.z); av[7] = (short)f2bf(v1.w);
            }
            a[rt] = av;
        }
#pragma unroll
        for (int j = 0; j < 8; ++j) {
            bf16x8 b = *(const bf16x8*)&wl[((size_t)(j * 4 + k0) * 64 + lane) * 8];
            acc[0][j] = __builtin_amdgcn_mfma_f32_16x16x32_bf16(a[0], b, acc[0][j], 0, 0, 0);
            acc[1][j] = __builtin_amdgcn_mfma_f32_16x16x32_bf16(a[1], b, acc[1][j], 0, 0, 0);
        }
    }

    // C/D layout: col = lane&15, row = 4*(lane>>4) + r
#pragma unroll
    for (int rt = 0; rt < 2; ++rt) {
#pragma unroll
        for (int r = 0; r < 4; ++r) {
            int row = m0 + rt * 16 + 4 * kc + r;
            if (row < N) {
#pragma unroll
                for (int j = 0; j < 8; ++j) {
                    H[(size_t)row * 128 + j * 16 + mrow] = f2bf(acc[rt][j][r]);
                }
            }
        }
    }
}

// ---------------- Fused: g1 = relu(Ahat*h1 + b1); h2 = g1 @ W2 (bf16 out) ---
// One wave per node. g1 fp32 in registers. All w2r reg indices compile-time;
// bank stagger folded into the preload ADDRESS.

__global__ __launch_bounds__(256) void agg128_fused_kernel(const unsigned short* __restrict__ H,
                                                           const int* __restrict__ ell,
                                                           const int* __restrict__ deg,
                                                           const float* __restrict__ dinv,
                                                           const float* __restrict__ b1,
                                                           const float* __restrict__ W2,
                                                           unsigned short* __restrict__ h2out, int N) {
    __shared__ float gbuf[4][128];
    int lane = threadIdx.x & 63;
    int w = threadIdx.x >> 6;
    int i = blockIdx.x * 4 + w;
    if (i >= N) return;

    int n = lane & 15;
    int q = lane >> 4;

    float w2r[32];
#pragma unroll
    for (int m = 0; m < 32; ++m) {
        int mm = (m + 8 * q) & 31;                 // runtime address, constant index
        w2r[m] = W2[(size_t)(q * 32 + mm) * 16 + n];
    }

    int d = deg[i]; if (d > ELL_W) d = ELL_W;
    float di = dinv[i];

    ushort2 hv = *(const ushort2*)&H[(size_t)i * 128 + 2 * lane];
    float ax = di * bf2f(hv.x);
    float ay = di * bf2f(hv.y);

    const int* row = &ell[(size_t)i * ELL_W];
#pragma unroll 4
    for (int e = 0; e < d; ++e) {
        int s = row[e];
        float wt = dinv[s];
        ushort2 h2 = *(const ushort2*)&H[(size_t)s * 128 + 2 * lane];
        ax += wt * bf2f(h2.x);
        ay += wt * bf2f(h2.y);
    }
    float2 bb = *(const float2*)&b1[2 * lane];
    float gx = fmaxf(di * ax + bb.x, 0.f);
    float gy = fmaxf(di * ay + bb.y, 0.f);

    *(float2*)&gbuf[w][2 * lane] = make_float2(gx, gy);
    asm volatile("s_waitcnt lgkmcnt(0)" ::: "memory");   // wave-internal LDS RAW

    float partial = 0.f;
#pragma unroll
    for (int t = 0; t < 8; ++t) {
        int off = (t * 4 + 8 * q) & 31;                  // staggered: conflict-free
        float4 gv = *(const float4*)&gbuf[w][q * 32 + off];
        partial += gv.x * w2r[t * 4 + 0] + gv.y * w2r[t * 4 + 1] +
                   gv.z * w2r[t * 4 + 2] + gv.w * w2r[t * 4 + 3];
    }
    partial += __shfl_xor(partial, 16, 64);
    partial += __shfl_xor(partial, 32, 64);
    if (lane < 16) h2out[(size_t)i * 16 + lane] = f2bf(partial);
}

// ---------------- agg16: out = Ahat*h2 + b2 (fp32 out) ----------------

__global__ __launch_bounds__(256) void agg16_kernel(const unsigned short* __restrict__ H,
                                                    const int* __restrict__ ell,
                                                    const int* __restrict__ deg,
                                                    const float* __restrict__ dinv,
                                                    const float* __restrict__ b2,
                                                    float* __restrict__ out, int N) {
    int lane = threadIdx.x & 63;
    int i = blockIdx.x * 4 + (threadIdx.x >> 6);
    if (i >= N) return;
    int t = lane & 15;
    int q = lane >> 4;

    int d = deg[i]; if (d > ELL_W) d = ELL_W;
    float di = dinv[i];
    const int* row = &ell[(size_t)i * ELL_W];

    float partial = (q == 0) ? di * bf2f(H[(size_t)i * 16 + t]) : 0.f;
#pragma unroll 2
    for (int e = q; e < d; e += 4) {
        int s = row[e];
        float wt = dinv[s];
        partial += wt * bf2f(H[(size_t)s * 16 + t]);
    }
    partial += __shfl_xor(partial, 16, 64);
    partial += __shfl_xor(partial, 32, 64);
    if (lane < 16) out[(size_t)i * 16 + t] = di * partial + b2[t];
}

// ---------------- Launch ----------------

extern "C" void kernel_launch(void* const* d_in, const int* in_sizes, int n_in,
                              void* d_out, int out_size, void* d_ws, size_t ws_size,
                              hipStream_t stream) {
    const float* x = (const float*)d_in[0];
    const int* ei = (const int*)d_in[1];
    const float* W1 = (const float*)d_in[2];
    const float* b1 = (const float*)d_in[3];
    const float* W2 = (const float*)d_in[4];
    const float* b2 = (const float*)d_in[5];
    float* out = (float*)d_out;

    const int N = in_sizes[0] / 128;   // 100000
    const int E = in_sizes[1] / 2;     // 1600000
    const int NB = (N + (1 << BSH) - 1) >> BSH;   // 391 buckets

    char* base = (char*)d_ws;
    size_t off = 0;
    auto align_up = [](size_t v) { return (v + 255) & ~(size_t)255; };

    int* cursor = (int*)(base + off);                      off = align_up(off + (size_t)N * 4);
    float* dinv = (float*)(base + off);                    off = align_up(off + (size_t)N * 4);
    int* ell = (int*)(base + off);                         off = align_up(off + (size_t)N * ELL_W * 4);
    int* gcur = (int*)(base + off);                        off = align_up(off + (size_t)NB * 16 * 4);
    int* bucket = (int*)(base + off);                      off = align_up(off + (size_t)NB * BCAP * 4);
    unsigned short* wfrag = (unsigned short*)(base + off); off = align_up(off + (size_t)16384 * 2);
    unsigned short* h1 = (unsigned short*)(base + off);    off = align_up(off + (size_t)N * 128 * 2);
    unsigned short* h2 = (unsigned short*)(base + off);    off = align_up(off + (size_t)N * 16 * 2);

    zero_kernel<<<(N + 255) / 256, 256, 0, stream>>>(cursor, N);
    zero_kernel<<<(NB * 16 + 255) / 256, 256, 0, stream>>>(gcur, NB * 16);
    build_wfrag_kernel<<<8, 256, 0, stream>>>(W1, wfrag);

    int nchunks = (E + CHUNK - 1) / CHUNK;
    p1_partition_kernel<<<nchunks, 256, 0, stream>>>(ei, E, N, NB, gcur, bucket);
    p2_ell_kernel<<<NB, 256, 0, stream>>>(bucket, gcur, N, cursor, ell);
    compute_dinv_kernel<<<(N + 255) / 256, 256, 0, stream>>>(cursor, dinv, N);

    gemm1_mfma_kernel<<<(N + 127) / 128, 256, 0, stream>>>(x, wfrag, h1, N);
    agg128_fused_kernel<<<(N + 3) / 4, 256, 0, stream>>>(h1, ell, cursor, dinv, b1, W2, h2, N);
    agg16_kernel<<<(N + 3) / 4, 256, 0, stream>>>(h2, ell, cursor, dinv, b2, out, N);
}

// Round 7
// 228.425 us; speedup vs baseline: 2.2689x; 1.0130x over previous
//
#include <hip/hip_runtime.h>
#include <hip/hip_bf16.h>

typedef __attribute__((ext_vector_type(8))) short bf16x8;
typedef __attribute__((ext_vector_type(4))) float f32x4;

#define ELL_W 64        // Poisson(16) in-degree: P(deg>64) ~ 1e-20
#define BSH   8         // 256 dst-nodes per bucket
#define BCAP  4608      // bucket capacity: mean 4096 + 8 sigma
#define CHUNK 4096      // edges per block in p1

// ---------------- helpers ----------------

__device__ __forceinline__ float bf2f(unsigned short u) {
    return __uint_as_float(((unsigned int)u) << 16);
}
__device__ __forceinline__ unsigned short f2bf(float f) {
    unsigned int u = __float_as_uint(f);
    unsigned int r = (u + 0x7fffu + ((u >> 16) & 1u)) >> 16;  // RNE
    return (unsigned short)r;
}

__global__ void zero_kernel(int* __restrict__ a, int n) {
    int i = blockIdx.x * blockDim.x + threadIdx.x;
    if (i < n) a[i] = 0;
}

// ---------------- P1: partition edges into dst-buckets ----------------

__global__ __launch_bounds__(256) void p1_partition_kernel(const int* __restrict__ ei, int E, int N, int NB,
                                                           int* __restrict__ gcur, int* __restrict__ bucket) {
    __shared__ int hist[512];
    __shared__ int gbase[512];
    __shared__ int cur2[512];
    int tid = threadIdx.x;
    int c0 = blockIdx.x * CHUNK;

    for (int i = tid; i < NB; i += 256) { hist[i] = 0; cur2[i] = 0; }
    __syncthreads();

    int rec[16], bkt[16];
#pragma unroll
    for (int k = 0; k < 16; ++k) {
        int e = c0 + k * 256 + tid;
        int b = -1, r = 0;
        if (e < E) {
            int s = ei[e], d = ei[E + e];
            if ((unsigned)s < (unsigned)N && (unsigned)d < (unsigned)N) {
                b = d >> BSH;
                r = (s << BSH) | (d & ((1 << BSH) - 1));
            }
        }
        bkt[k] = b; rec[k] = r;
        if (b >= 0) atomicAdd(&hist[b], 1);
    }
    __syncthreads();

    for (int i = tid; i < NB; i += 256) {
        int c = hist[i];
        gbase[i] = (c > 0) ? atomicAdd(&gcur[i * 16], c) : 0;
    }
    __syncthreads();

#pragma unroll
    for (int k = 0; k < 16; ++k) {
        int b = bkt[k];
        if (b >= 0) {
            int r = atomicAdd(&cur2[b], 1);
            int pos = gbase[b] + r;
            if (pos < BCAP) bucket[(size_t)b * BCAP + pos] = rec[k];
        }
    }
}

// ---------------- P2: bucket -> ELL (one block per bucket) ----------------

__global__ __launch_bounds__(256) void p2_ell_kernel(const int* __restrict__ bucket,
                                                     const int* __restrict__ gcur, int N,
                                                     int* __restrict__ cursor, int* __restrict__ ell) {
    int b = blockIdx.x;
    int cnt = gcur[b * 16]; if (cnt > BCAP) cnt = BCAP;
    const int* reg = &bucket[(size_t)b * BCAP];
    for (int k = threadIdx.x; k < cnt; k += 256) {
        int rec = reg[k];
        int s = (int)(((unsigned)rec) >> BSH);
        int dst = (b << BSH) | (rec & ((1 << BSH) - 1));
        if (dst < N) {
            int pos = atomicAdd(&cursor[dst], 1);
            if (pos < ELL_W) ell[(size_t)dst * ELL_W + pos] = s;
        }
    }
}

__global__ void compute_dinv_kernel(const int* __restrict__ deg, float* __restrict__ dinv, int N) {
    int i = blockIdx.x * blockDim.x + threadIdx.x;
    if (i < N) dinv[i] = rsqrtf((float)(deg[i] + 1));   // +1 self-loop
}

// ---------------- W1 -> bf16 fragment-ordered pack ----------------

__global__ void build_wfrag_kernel(const float* __restrict__ W1, unsigned short* __restrict__ wfrag) {
    int t = blockIdx.x * blockDim.x + threadIdx.x;   // 0..2047, 8 elems each
    if (t >= 2048) return;
    int ln = t & 63;
    int blk = t >> 6;          // j*4 + k0
    int j = blk >> 2, k0 = blk & 3;
    int nn = ln & 15, cc = ln >> 4;
    int n = j * 16 + nn;
    unsigned short tmp[8];
#pragma unroll
    for (int i = 0; i < 8; ++i) {
        int k = k0 * 32 + cc * 8 + i;
        tmp[i] = f2bf(W1[(size_t)k * 128 + n]);
    }
    *(uint4*)&wfrag[(size_t)t * 8] = *(const uint4*)tmp;
}

// ---------------- GEMM1 (MFMA): h1'[N,128](bf16) = dinv .* (bf16(X) @ W1) --
// Epilogue scales each output row by dinv[row] (pre-weighted table).

__global__ __launch_bounds__(256) void gemm1_mfma_kernel(const float* __restrict__ X,
                                                         const unsigned short* __restrict__ wfrag,
                                                         const float* __restrict__ dinv,
                                                         unsigned short* __restrict__ H, int N) {
    __shared__ __align__(16) unsigned short wl[16384];   // 32 KB
    int tid = threadIdx.x;
    {
        uint4* dst = (uint4*)wl;
        const uint4* src = (const uint4*)wfrag;
        for (int idx = tid; idx < 2048; idx += 256) dst[idx] = src[idx];
    }
    __syncthreads();

    int lane = tid & 63;
    int wave = tid >> 6;
    int m0 = blockIdx.x * 128 + wave * 32;
    int mrow = lane & 15;
    int kc = lane >> 4;

    f32x4 acc[2][8];
#pragma unroll
    for (int rt = 0; rt < 2; ++rt)
#pragma unroll
        for (int j = 0; j < 8; ++j) acc[rt][j] = (f32x4)(0.f);

#pragma unroll
    for (int k0 = 0; k0 < 4; ++k0) {
        bf16x8 a[2];
#pragma unroll
        for (int rt = 0; rt < 2; ++rt) {
            int row = m0 + rt * 16 + mrow;
            bf16x8 av = (bf16x8)(short)0;
            if (row < N) {
                const float4* p = (const float4*)&X[(size_t)row * 128 + k0 * 32 + kc * 8];
                float4 v0 = p[0], v1 = p[1];
                av[0] = (short)f2bf(v0.x); av[1] = (short)f2bf(v0.y);
                av[2] = (short)f2bf(v0.z); av[3] = (short)f2bf(v0.w);
                av[4] = (short)f2bf(v1.x); av[5] = (short)f2bf(v1.y);
                av[6] = (short)f2bf(v1.z); av[7] = (short)f2bf(v1.w);
            }
            a[rt] = av;
        }
#pragma unroll
        for (int j = 0; j < 8; ++j) {
            bf16x8 b = *(const bf16x8*)&wl[((size_t)(j * 4 + k0) * 64 + lane) * 8];
            acc[0][j] = __builtin_amdgcn_mfma_f32_16x16x32_bf16(a[0], b, acc[0][j], 0, 0, 0);
            acc[1][j] = __builtin_amdgcn_mfma_f32_16x16x32_bf16(a[1], b, acc[1][j], 0, 0, 0);
        }
    }

    // C/D layout: col = lane&15, row = 4*(lane>>4) + r ; scale by dinv[row]
#pragma unroll
    for (int rt = 0; rt < 2; ++rt) {
#pragma unroll
        for (int r = 0; r < 4; ++r) {
            int row = m0 + rt * 16 + 4 * kc + r;
            if (row < N) {
                float dv = dinv[row];
#pragma unroll
                for (int j = 0; j < 8; ++j) {
                    H[(size_t)row * 128 + j * 16 + mrow] = f2bf(dv * acc[rt][j][r]);
                }
            }
        }
    }
}

// ---------------- Fused: g1 = relu(di*Σh1' + b1); h2' = di*(g1 @ W2) -------
// Weightless aggregation: per edge = broadcast idx + one 4B/lane gather + add.
// 8 gathers in flight (two int4 index loads), 2 accumulator pairs for ILP.

__global__ __launch_bounds__(256) void agg128_fused_kernel(const unsigned short* __restrict__ H,
                                                           const int* __restrict__ ell,
                                                           const int* __restrict__ deg,
                                                           const float* __restrict__ dinv,
                                                           const float* __restrict__ b1,
                                                           const float* __restrict__ W2,
                                                           unsigned short* __restrict__ h2out, int N) {
    __shared__ float gbuf[4][128];
    int lane = threadIdx.x & 63;
    int w = threadIdx.x >> 6;
    int i = blockIdx.x * 4 + w;
    if (i >= N) return;

    int n = lane & 15;
    int q = lane >> 4;

    float w2r[32];
#pragma unroll
    for (int m = 0; m < 32; ++m) {
        int mm = (m + 8 * q) & 31;                 // runtime address, constant reg index
        w2r[m] = W2[(size_t)(q * 32 + mm) * 16 + n];
    }

    int d = deg[i]; if (d > ELL_W) d = ELL_W;
    float di = dinv[i];

    ushort2 hv = *(const ushort2*)&H[(size_t)i * 128 + 2 * lane];
    float ax = bf2f(hv.x), ay = bf2f(hv.y);    // self term = h1'[i]
    float bx = 0.f, by = 0.f;

    const int* row = &ell[(size_t)i * ELL_W];
    int e = 0;
    for (; e + 8 <= d; e += 8) {
        int4 sA = *(const int4*)&row[e];
        int4 sB = *(const int4*)&row[e + 4];
        ushort2 g0 = *(const ushort2*)&H[(size_t)sA.x * 128 + 2 * lane];
        ushort2 g1 = *(const ushort2*)&H[(size_t)sA.y * 128 + 2 * lane];
        ushort2 g2 = *(const ushort2*)&H[(size_t)sA.z * 128 + 2 * lane];
        ushort2 g3 = *(const ushort2*)&H[(size_t)sA.w * 128 + 2 * lane];
        ushort2 g4 = *(const ushort2*)&H[(size_t)sB.x * 128 + 2 * lane];
        ushort2 g5 = *(const ushort2*)&H[(size_t)sB.y * 128 + 2 * lane];
        ushort2 g6 = *(const ushort2*)&H[(size_t)sB.z * 128 + 2 * lane];
        ushort2 g7 = *(const ushort2*)&H[(size_t)sB.w * 128 + 2 * lane];
        ax += bf2f(g0.x); ay += bf2f(g0.y);
        bx += bf2f(g1.x); by += bf2f(g1.y);
        ax += bf2f(g2.x); ay += bf2f(g2.y);
        bx += bf2f(g3.x); by += bf2f(g3.y);
        ax += bf2f(g4.x); ay += bf2f(g4.y);
        bx += bf2f(g5.x); by += bf2f(g5.y);
        ax += bf2f(g6.x); ay += bf2f(g6.y);
        bx += bf2f(g7.x); by += bf2f(g7.y);
    }
    for (; e < d; ++e) {
        int s = row[e];
        ushort2 g = *(const ushort2*)&H[(size_t)s * 128 + 2 * lane];
        ax += bf2f(g.x); ay += bf2f(g.y);
    }
    ax += bx; ay += by;

    float2 bb = *(const float2*)&b1[2 * lane];
    float gx = fmaxf(di * ax + bb.x, 0.f);
    float gy = fmaxf(di * ay + bb.y, 0.f);

    *(float2*)&gbuf[w][2 * lane] = make_float2(gx, gy);
    asm volatile("s_waitcnt lgkmcnt(0)" ::: "memory");   // wave-internal LDS RAW

    float partial = 0.f;
#pragma unroll
    for (int t = 0; t < 8; ++t) {
        int off = (t * 4 + 8 * q) & 31;                  // staggered: conflict-free
        float4 gv = *(const float4*)&gbuf[w][q * 32 + off];
        partial += gv.x * w2r[t * 4 + 0] + gv.y * w2r[t * 4 + 1] +
                   gv.z * w2r[t * 4 + 2] + gv.w * w2r[t * 4 + 3];
    }
    partial += __shfl_xor(partial, 16, 64);
    partial += __shfl_xor(partial, 32, 64);
    // store h2' = dinv[i] * h2[i]
    if (lane < 16) h2out[(size_t)i * 16 + lane] = f2bf(di * partial);
}

// ---------------- agg16: out = di*(Σ h2' + h2'[i]) + b2 (fp32 out) --------

__global__ __launch_bounds__(256) void agg16_kernel(const unsigned short* __restrict__ H,
                                                    const int* __restrict__ ell,
                                                    const int* __restrict__ deg,
                                                    const float* __restrict__ dinv,
                                                    const float* __restrict__ b2,
                                                    float* __restrict__ out, int N) {
    int lane = threadIdx.x & 63;
    int i = blockIdx.x * 4 + (threadIdx.x >> 6);
    if (i >= N) return;
    int t = lane & 15;
    int q = lane >> 4;

    int d = deg[i]; if (d > ELL_W) d = ELL_W;
    float di = dinv[i];
    const int* row = &ell[(size_t)i * ELL_W];

    float partial = (q == 0) ? bf2f(H[(size_t)i * 16 + t]) : 0.f;
#pragma unroll 2
    for (int e = q; e < d; e += 4) {
        int s = row[e];
        partial += bf2f(H[(size_t)s * 16 + t]);
    }
    partial += __shfl_xor(partial, 16, 64);
    partial += __shfl_xor(partial, 32, 64);
    if (lane < 16) out[(size_t)i * 16 + t] = di * partial + b2[t];
}

// ---------------- Launch ----------------

extern "C" void kernel_launch(void* const* d_in, const int* in_sizes, int n_in,
                              void* d_out, int out_size, void* d_ws, size_t ws_size,
                              hipStream_t stream) {
    const float* x = (const float*)d_in[0];
    const int* ei = (const int*)d_in[1];
    const float* W1 = (const float*)d_in[2];
    const float* b1 = (const float*)d_in[3];
    const float* W2 = (const float*)d_in[4];
    const float* b2 = (const float*)d_in[5];
    float* out = (float*)d_out;

    const int N = in_sizes[0] / 128;   // 100000
    const int E = in_sizes[1] / 2;     // 1600000
    const int NB = (N + (1 << BSH) - 1) >> BSH;   // 391 buckets

    char* base = (char*)d_ws;
    size_t off = 0;
    auto align_up = [](size_t v) { return (v + 255) & ~(size_t)255; };

    int* cursor = (int*)(base + off);                      off = align_up(off + (size_t)N * 4);
    float* dinv = (float*)(base + off);                    off = align_up(off + (size_t)N * 4);
    int* ell = (int*)(base + off);                         off = align_up(off + (size_t)N * ELL_W * 4);
    int* gcur = (int*)(base + off);                        off = align_up(off + (size_t)NB * 16 * 4);
    int* bucket = (int*)(base + off);                      off = align_up(off + (size_t)NB * BCAP * 4);
    unsigned short* wfrag = (unsigned short*)(base + off); off = align_up(off + (size_t)16384 * 2);
    unsigned short* h1 = (unsigned short*)(base + off);    off = align_up(off + (size_t)N * 128 * 2);
    unsigned short* h2 = (unsigned short*)(base + off);    off = align_up(off + (size_t)N * 16 * 2);

    zero_kernel<<<(N + 255) / 256, 256, 0, stream>>>(cursor, N);
    zero_kernel<<<(NB * 16 + 255) / 256, 256, 0, stream>>>(gcur, NB * 16);
    build_wfrag_kernel<<<8, 256, 0, stream>>>(W1, wfrag);

    int nchunks = (E + CHUNK - 1) / CHUNK;
    p1_partition_kernel<<<nchunks, 256, 0, stream>>>(ei, E, N, NB, gcur, bucket);
    p2_ell_kernel<<<NB, 256, 0, stream>>>(bucket, gcur, N, cursor, ell);
    compute_dinv_kernel<<<(N + 255) / 256, 256, 0, stream>>>(cursor, dinv, N);

    gemm1_mfma_kernel<<<(N + 127) / 128, 256, 0, stream>>>(x, wfrag, dinv, h1, N);
    agg128_fused_kernel<<<(N + 3) / 4, 256, 0, stream>>>(h1, ell, cursor, dinv, b1, W2, h2, N);
    agg16_kernel<<<(N + 3) / 4, 256, 0, stream>>>(h2, ell, cursor, dinv, b2, out, N);
}

// Round 8
// 214.497 us; speedup vs baseline: 2.4162x; 1.0649x over previous
//
#include <hip/hip_runtime.h>
#include <hip/hip_bf16.h>

typedef __attribute__((ext_vector_type(8))) short bf16x8;
typedef __attribute__((ext_vector_type(4))) float f32x4;

#define ELL_W 64        // Poisson(16) in-degree: P(deg>64) ~ 1e-20
#define BSH   8         // 256 dst-nodes per bucket
#define BCAP  4608      // bucket capacity: mean 4096 + 8 sigma
#define CHUNK 4096      // edges per block in p1

// ---------------- helpers ----------------

__device__ __forceinline__ float bf2f(unsigned short u) {
    return __uint_as_float(((unsigned int)u) << 16);
}
__device__ __forceinline__ unsigned short f2bf(float f) {
    unsigned int u = __float_as_uint(f);
    unsigned int r = (u + 0x7fffu + ((u >> 16) & 1u)) >> 16;  // RNE
    return (unsigned short)r;
}

__global__ void zero_kernel(int* __restrict__ a, int n) {
    int i = blockIdx.x * blockDim.x + threadIdx.x;
    if (i < n) a[i] = 0;
}

// ---------------- P1: partition edges into dst-buckets ----------------

__global__ __launch_bounds__(256) void p1_partition_kernel(const int* __restrict__ ei, int E, int N, int NB,
                                                           int* __restrict__ gcur, int* __restrict__ bucket) {
    __shared__ int hist[512];
    __shared__ int gbase[512];
    __shared__ int cur2[512];
    int tid = threadIdx.x;
    int c0 = blockIdx.x * CHUNK;

    for (int i = tid; i < NB; i += 256) { hist[i] = 0; cur2[i] = 0; }
    __syncthreads();

    int rec[16], bkt[16];
#pragma unroll
    for (int k = 0; k < 16; ++k) {
        int e = c0 + k * 256 + tid;
        int b = -1, r = 0;
        if (e < E) {
            int s = ei[e], d = ei[E + e];
            if ((unsigned)s < (unsigned)N && (unsigned)d < (unsigned)N) {
                b = d >> BSH;
                r = (s << BSH) | (d & ((1 << BSH) - 1));
            }
        }
        bkt[k] = b; rec[k] = r;
        if (b >= 0) atomicAdd(&hist[b], 1);
    }
    __syncthreads();

    for (int i = tid; i < NB; i += 256) {
        int c = hist[i];
        gbase[i] = (c > 0) ? atomicAdd(&gcur[i * 16], c) : 0;
    }
    __syncthreads();

#pragma unroll
    for (int k = 0; k < 16; ++k) {
        int b = bkt[k];
        if (b >= 0) {
            int r = atomicAdd(&cur2[b], 1);
            int pos = gbase[b] + r;
            if (pos < BCAP) bucket[(size_t)b * BCAP + pos] = rec[k];
        }
    }
}

// ---------------- P2: bucket -> ELL (one block per bucket) ----------------

__global__ __launch_bounds__(256) void p2_ell_kernel(const int* __restrict__ bucket,
                                                     const int* __restrict__ gcur, int N,
                                                     int* __restrict__ cursor, int* __restrict__ ell) {
    int b = blockIdx.x;
    int cnt = gcur[b * 16]; if (cnt > BCAP) cnt = BCAP;
    const int* reg = &bucket[(size_t)b * BCAP];
    for (int k = threadIdx.x; k < cnt; k += 256) {
        int rec = reg[k];
        int s = (int)(((unsigned)rec) >> BSH);
        int dst = (b << BSH) | (rec & ((1 << BSH) - 1));
        if (dst < N) {
            int pos = atomicAdd(&cursor[dst], 1);
            if (pos < ELL_W) ell[(size_t)dst * ELL_W + pos] = s;
        }
    }
}

// ---------------- pad: round each ELL row up to 4 with dummy node N; ------
// ---------------- zero h1'[N] so pad gathers contribute 0 -----------------

__global__ void pad_kernel(const int* __restrict__ deg, int N,
                           int* __restrict__ ell, unsigned short* __restrict__ h1) {
    int i = blockIdx.x * blockDim.x + threadIdx.x;
    if (i < 128) h1[(size_t)N * 128 + i] = 0;
    if (i < N) {
        int d = deg[i]; if (d > ELL_W) d = ELL_W;
        int d4 = (d + 3) & ~3; if (d4 > ELL_W) d4 = ELL_W;
        for (int k = d; k < d4; ++k) ell[(size_t)i * ELL_W + k] = N;
    }
}

__global__ void compute_dinv_kernel(const int* __restrict__ deg, float* __restrict__ dinv, int N) {
    int i = blockIdx.x * blockDim.x + threadIdx.x;
    if (i < N) dinv[i] = rsqrtf((float)(deg[i] + 1));   // +1 self-loop
}

// ---------------- W1 -> bf16 fragment-ordered pack ----------------

__global__ void build_wfrag_kernel(const float* __restrict__ W1, unsigned short* __restrict__ wfrag) {
    int t = blockIdx.x * blockDim.x + threadIdx.x;   // 0..2047, 8 elems each
    if (t >= 2048) return;
    int ln = t & 63;
    int blk = t >> 6;          // j*4 + k0
    int j = blk >> 2, k0 = blk & 3;
    int nn = ln & 15, cc = ln >> 4;
    int n = j * 16 + nn;
    unsigned short tmp[8];
#pragma unroll
    for (int i = 0; i < 8; ++i) {
        int k = k0 * 32 + cc * 8 + i;
        tmp[i] = f2bf(W1[(size_t)k * 128 + n]);
    }
    *(uint4*)&wfrag[(size_t)t * 8] = *(const uint4*)tmp;
}

// ---------------- GEMM1 (MFMA): h1'[N,128](bf16) = dinv .* (bf16(X) @ W1) --

__global__ __launch_bounds__(256) void gemm1_mfma_kernel(const float* __restrict__ X,
                                                         const unsigned short* __restrict__ wfrag,
                                                         const float* __restrict__ dinv,
                                                         unsigned short* __restrict__ H, int N) {
    __shared__ __align__(16) unsigned short wl[16384];   // 32 KB
    int tid = threadIdx.x;
    {
        uint4* dst = (uint4*)wl;
        const uint4* src = (const uint4*)wfrag;
        for (int idx = tid; idx < 2048; idx += 256) dst[idx] = src[idx];
    }
    __syncthreads();

    int lane = tid & 63;
    int wave = tid >> 6;
    int m0 = blockIdx.x * 128 + wave * 32;
    int mrow = lane & 15;
    int kc = lane >> 4;

    f32x4 acc[2][8];
#pragma unroll
    for (int rt = 0; rt < 2; ++rt)
#pragma unroll
        for (int j = 0; j < 8; ++j) acc[rt][j] = (f32x4)(0.f);

#pragma unroll
    for (int k0 = 0; k0 < 4; ++k0) {
        bf16x8 a[2];
#pragma unroll
        for (int rt = 0; rt < 2; ++rt) {
            int row = m0 + rt * 16 + mrow;
            bf16x8 av = (bf16x8)(short)0;
            if (row < N) {
                const float4* p = (const float4*)&X[(size_t)row * 128 + k0 * 32 + kc * 8];
                float4 v0 = p[0], v1 = p[1];
                av[0] = (short)f2bf(v0.x); av[1] = (short)f2bf(v0.y);
                av[2] = (short)f2bf(v0.z); av[3] = (short)f2bf(v0.w);
                av[4] = (short)f2bf(v1.x); av[5] = (short)f2bf(v1.y);
                av[6] = (short)f2bf(v1.z); av[7] = (short)f2bf(v1.w);
            }
            a[rt] = av;
        }
#pragma unroll
        for (int j = 0; j < 8; ++j) {
            bf16x8 b = *(const bf16x8*)&wl[((size_t)(j * 4 + k0) * 64 + lane) * 8];
            acc[0][j] = __builtin_amdgcn_mfma_f32_16x16x32_bf16(a[0], b, acc[0][j], 0, 0, 0);
            acc[1][j] = __builtin_amdgcn_mfma_f32_16x16x32_bf16(a[1], b, acc[1][j], 0, 0, 0);
        }
    }

    // C/D layout: col = lane&15, row = 4*(lane>>4) + r ; scale by dinv[row]
#pragma unroll
    for (int rt = 0; rt < 2; ++rt) {
#pragma unroll
        for (int r = 0; r < 4; ++r) {
            int row = m0 + rt * 16 + 4 * kc + r;
            if (row < N) {
                float dv = dinv[row];
#pragma unroll
                for (int j = 0; j < 8; ++j) {
                    H[(size_t)row * 128 + j * 16 + mrow] = f2bf(dv * acc[rt][j][r]);
                }
            }
        }
    }
}

// ---------------- Fused: g1 = relu(di*Σh1' + b1); h2' = di*(g1 @ W2) -------
// Wave processes 4 nodes (W2 regs amortized). Pair-gather: lane sub=l>>5
// picks edge e+sub, fl=l&31 owns features 4fl..4fl+3 (ushort4 = 8B/lane);
// ONE VMEM instruction fetches a 256B row for each of 2 edges. Halves
// combined with shfl_xor(32). ELL rows padded to x4 with zero-row N.

__global__ __launch_bounds__(256) void agg128_fused_kernel(const unsigned short* __restrict__ H,
                                                           const int* __restrict__ ell,
                                                           const int* __restrict__ deg,
                                                           const float* __restrict__ dinv,
                                                           const float* __restrict__ b1,
                                                           const float* __restrict__ W2,
                                                           unsigned short* __restrict__ h2out, int N) {
    __shared__ float gbuf[4][128];
    int lane = threadIdx.x & 63;
    int w = threadIdx.x >> 6;
    int i0 = blockIdx.x * 16 + w * 4;

    int n = lane & 15;
    int q = lane >> 4;
    int sub = lane >> 5;      // which edge of the pair
    int fl = lane & 31;       // feature group: 4fl..4fl+3

    float w2r[32];
#pragma unroll
    for (int m = 0; m < 32; ++m) {
        int mm = (m + 8 * q) & 31;                 // runtime address, constant reg index
        w2r[m] = W2[(size_t)(q * 32 + mm) * 16 + n];
    }

    for (int nn = 0; nn < 4; ++nn) {
        int i = i0 + nn;
        if (i >= N) break;
        int d = deg[i]; if (d > ELL_W) d = ELL_W;
        int d4 = (d + 3) & ~3; if (d4 > ELL_W) d4 = ELL_W;
        float di = dinv[i];

        // self term once (sub==0 half only; halves are summed later)
        ushort4 hv = *(const ushort4*)&H[(size_t)i * 128 + 4 * fl];
        float a0 = sub ? 0.f : bf2f(hv.x);
        float a1 = sub ? 0.f : bf2f(hv.y);
        float a2 = sub ? 0.f : bf2f(hv.z);
        float a3 = sub ? 0.f : bf2f(hv.w);

        const int* row = &ell[(size_t)i * ELL_W];
        for (int e = 0; e < d4; e += 4) {
            int4 sv = *(const int4*)&row[e];
            int sA = sub ? sv.y : sv.x;
            int sB = sub ? sv.w : sv.z;
            ushort4 gA = *(const ushort4*)&H[(size_t)sA * 128 + 4 * fl];
            ushort4 gB = *(const ushort4*)&H[(size_t)sB * 128 + 4 * fl];
            a0 += bf2f(gA.x) + bf2f(gB.x);
            a1 += bf2f(gA.y) + bf2f(gB.y);
            a2 += bf2f(gA.z) + bf2f(gB.z);
            a3 += bf2f(gA.w) + bf2f(gB.w);
        }

        // combine the two half-wave partials
        a0 += __shfl_xor(a0, 32, 64);
        a1 += __shfl_xor(a1, 32, 64);
        a2 += __shfl_xor(a2, 32, 64);
        a3 += __shfl_xor(a3, 32, 64);

        if (sub == 0) {
            float4 bb = *(const float4*)&b1[4 * fl];
            float4 gv;
            gv.x = fmaxf(di * a0 + bb.x, 0.f);
            gv.y = fmaxf(di * a1 + bb.y, 0.f);
            gv.z = fmaxf(di * a2 + bb.z, 0.f);
            gv.w = fmaxf(di * a3 + bb.w, 0.f);
            *(float4*)&gbuf[w][4 * fl] = gv;
        }
        asm volatile("s_waitcnt lgkmcnt(0)" ::: "memory");   // wave-internal LDS RAW

        float partial = 0.f;
#pragma unroll
        for (int t = 0; t < 8; ++t) {
            int off = (t * 4 + 8 * q) & 31;                  // staggered: conflict-free
            float4 gv = *(const float4*)&gbuf[w][q * 32 + off];
            partial += gv.x * w2r[t * 4 + 0] + gv.y * w2r[t * 4 + 1] +
                       gv.z * w2r[t * 4 + 2] + gv.w * w2r[t * 4 + 3];
        }
        partial += __shfl_xor(partial, 16, 64);
        partial += __shfl_xor(partial, 32, 64);
        // store h2' = dinv[i] * h2[i]
        if (lane < 16) h2out[(size_t)i * 16 + lane] = f2bf(di * partial);
    }
}

// ---------------- agg16: out = di*(Σ h2' + h2'[i]) + b2 (fp32 out) --------

__global__ __launch_bounds__(256) void agg16_kernel(const unsigned short* __restrict__ H,
                                                    const int* __restrict__ ell,
                                                    const int* __restrict__ deg,
                                                    const float* __restrict__ dinv,
                                                    const float* __restrict__ b2,
                                                    float* __restrict__ out, int N) {
    int lane = threadIdx.x & 63;
    int i = blockIdx.x * 4 + (threadIdx.x >> 6);
    if (i >= N) return;
    int t = lane & 15;
    int q = lane >> 4;

    int d = deg[i]; if (d > ELL_W) d = ELL_W;
    float di = dinv[i];
    const int* row = &ell[(size_t)i * ELL_W];

    float partial = (q == 0) ? bf2f(H[(size_t)i * 16 + t]) : 0.f;
#pragma unroll 2
    for (int e = q; e < d; e += 4) {
        int s = row[e];
        partial += bf2f(H[(size_t)s * 16 + t]);
    }
    partial += __shfl_xor(partial, 16, 64);
    partial += __shfl_xor(partial, 32, 64);
    if (lane < 16) out[(size_t)i * 16 + t] = di * partial + b2[t];
}

// ---------------- Launch ----------------

extern "C" void kernel_launch(void* const* d_in, const int* in_sizes, int n_in,
                              void* d_out, int out_size, void* d_ws, size_t ws_size,
                              hipStream_t stream) {
    const float* x = (const float*)d_in[0];
    const int* ei = (const int*)d_in[1];
    const float* W1 = (const float*)d_in[2];
    const float* b1 = (const float*)d_in[3];
    const float* W2 = (const float*)d_in[4];
    const float* b2 = (const float*)d_in[5];
    float* out = (float*)d_out;

    const int N = in_sizes[0] / 128;   // 100000
    const int E = in_sizes[1] / 2;     // 1600000
    const int NB = (N + (1 << BSH) - 1) >> BSH;   // 391 buckets

    char* base = (char*)d_ws;
    size_t off = 0;
    auto align_up = [](size_t v) { return (v + 255) & ~(size_t)255; };

    int* cursor = (int*)(base + off);                      off = align_up(off + (size_t)N * 4);
    float* dinv = (float*)(base + off);                    off = align_up(off + (size_t)N * 4);
    int* ell = (int*)(base + off);                         off = align_up(off + (size_t)N * ELL_W * 4);
    int* gcur = (int*)(base + off);                        off = align_up(off + (size_t)NB * 16 * 4);
    int* bucket = (int*)(base + off);                      off = align_up(off + (size_t)NB * BCAP * 4);
    unsigned short* wfrag = (unsigned short*)(base + off); off = align_up(off + (size_t)16384 * 2);
    unsigned short* h1 = (unsigned short*)(base + off);    off = align_up(off + (size_t)(N + 1) * 128 * 2);
    unsigned short* h2 = (unsigned short*)(base + off);    off = align_up(off + (size_t)N * 16 * 2);

    zero_kernel<<<(N + 255) / 256, 256, 0, stream>>>(cursor, N);
    zero_kernel<<<(NB * 16 + 255) / 256, 256, 0, stream>>>(gcur, NB * 16);
    build_wfrag_kernel<<<8, 256, 0, stream>>>(W1, wfrag);

    int nchunks = (E + CHUNK - 1) / CHUNK;
    p1_partition_kernel<<<nchunks, 256, 0, stream>>>(ei, E, N, NB, gcur, bucket);
    p2_ell_kernel<<<NB, 256, 0, stream>>>(bucket, gcur, N, cursor, ell);
    pad_kernel<<<(N + 255) / 256, 256, 0, stream>>>(cursor, N, ell, h1);
    compute_dinv_kernel<<<(N + 255) / 256, 256, 0, stream>>>(cursor, dinv, N);

    gemm1_mfma_kernel<<<(N + 127) / 128, 256, 0, stream>>>(x, wfrag, dinv, h1, N);
    agg128_fused_kernel<<<(N + 15) / 16, 256, 0, stream>>>(h1, ell, cursor, dinv, b1, W2, h2, N);
    agg16_kernel<<<(N + 3) / 4, 256, 0, stream>>>(h2, ell, cursor, dinv, b2, out, N);
}